// Round 8
// baseline (268.930 us; speedup 1.0000x reference)
//
#include <hip/hip_runtime.h>
#include <hip/hip_bf16.h>
#include <cstdint>
#include <cstddef>

#define T_TOK 8192
#define H_DIM 768
#define I_DIM 1024
#define N_EXP 5
#define MAXTILE 136

typedef short v8s __attribute__((ext_vector_type(8)));
typedef float v4f __attribute__((ext_vector_type(4)));

static __device__ __forceinline__ unsigned short f2bf(float f) {
    union { float f; unsigned int u; } v; v.f = f;
    unsigned int u = v.u;
    unsigned int r = (u + 0x7fffu + ((u >> 16) & 1u)) >> 16;
    return (unsigned short)r;
}
static __device__ __forceinline__ float bf2f(unsigned short s) {
    union { unsigned int u; float f; } v; v.u = ((unsigned int)s) << 16; return v.f;
}

// async 16B global->LDS (wave-uniform LDS base + lane*16)
static __device__ __forceinline__ void async16(const unsigned short* g, unsigned short* l) {
    __builtin_amdgcn_global_load_lds(
        (const __attribute__((address_space(1))) unsigned int*)g,
        (__attribute__((address_space(3))) unsigned int*)l, 16, 0, 0);
}

// s_waitcnt vmcnt(4): vmcnt[3:0]=4, expcnt=7, lgkmcnt=15, vmcnt[15:14]=0
#define WAIT_VM4() __builtin_amdgcn_s_waitcnt(0x0F74)

// ---- prep: weight transposes (z<15) + router logits/top2 + x->bf16 (z>=15) ----
__global__ void k_prep(const float* __restrict__ gw, const float* __restrict__ uw,
                       const float* __restrict__ dw,
                       unsigned short* __restrict__ wbt, unsigned short* __restrict__ dbt,
                       const float* __restrict__ x, const float* __restrict__ rw,
                       const float* __restrict__ rb, unsigned short* __restrict__ xb,
                       int* __restrict__ top2e, float2* __restrict__ top2w) {
    const int z = blockIdx.z;
    const int tid = threadIdx.x;
    if (z < 3 * N_EXP) {
        __shared__ float tile[32][33];
        const int row = tid >> 3, cq = tid & 7;
        const int ocol = tid >> 3, seg = tid & 7;
        if (z < 2 * N_EXP) {
            if (blockIdx.y >= H_DIM / 32) return;
            const int e = z % N_EXP;
            const int isUp = z >= N_EXP;
            const float* src = (isUp ? uw : gw) + (size_t)e * H_DIM * I_DIM;
            const int c0 = blockIdx.x * 32, r0 = blockIdx.y * 32;
            float4 v = *(const float4*)(src + (size_t)(r0 + row) * I_DIM + c0 + cq * 4);
            tile[row][cq * 4 + 0] = v.x; tile[row][cq * 4 + 1] = v.y;
            tile[row][cq * 4 + 2] = v.z; tile[row][cq * 4 + 3] = v.w;
            __syncthreads();
            int c = c0 + ocol;
            int orow = (c >> 4) * 32 + (c & 15) + (isUp ? 16 : 0);
            ushort4 o;
            o.x = f2bf(tile[seg * 4 + 0][ocol]); o.y = f2bf(tile[seg * 4 + 1][ocol]);
            o.z = f2bf(tile[seg * 4 + 2][ocol]); o.w = f2bf(tile[seg * 4 + 3][ocol]);
            *(ushort4*)(wbt + ((size_t)e * 2 * I_DIM + orow) * H_DIM + r0 + seg * 4) = o;
        } else {
            if (blockIdx.x >= H_DIM / 32) return;
            const int e = z - 2 * N_EXP;
            const float* src = dw + (size_t)e * I_DIM * H_DIM;
            unsigned short* dst = dbt + (size_t)e * I_DIM * H_DIM;
            const int c0 = blockIdx.x * 32, r0 = blockIdx.y * 32;
            float4 v = *(const float4*)(src + (size_t)(r0 + row) * H_DIM + c0 + cq * 4);
            tile[row][cq * 4 + 0] = v.x; tile[row][cq * 4 + 1] = v.y;
            tile[row][cq * 4 + 2] = v.z; tile[row][cq * 4 + 3] = v.w;
            __syncthreads();
            ushort4 o;
            o.x = f2bf(tile[seg * 4 + 0][ocol]); o.y = f2bf(tile[seg * 4 + 1][ocol]);
            o.z = f2bf(tile[seg * 4 + 2][ocol]); o.w = f2bf(tile[seg * 4 + 3][ocol]);
            *(ushort4*)(dst + (size_t)(c0 + ocol) * I_DIM + r0 + seg * 4) = o;
        }
    } else {
        // router part: 2 z-slices x 1024 (x,y)-blocks x 4 waves = 8192 tokens
        const int wave = tid >> 6, lane = tid & 63;
        const int t = (((z - 3 * N_EXP) * 1024 + blockIdx.y * 32 + blockIdx.x) * 4) + wave;
        const float* xr = x + (size_t)t * H_DIM;
        unsigned short* xbr = xb + (size_t)t * H_DIM;
        float acc[N_EXP];
#pragma unroll
        for (int e = 0; e < N_EXP; e++) acc[e] = 0.f;
#pragma unroll
        for (int j = 0; j < H_DIM / 256; j++) {
            int idx = j * 256 + lane * 4;
            float4 xv = *(const float4*)(xr + idx);
            ushort4 o;
            o.x = f2bf(xv.x); o.y = f2bf(xv.y); o.z = f2bf(xv.z); o.w = f2bf(xv.w);
            *(ushort4*)(xbr + idx) = o;
#pragma unroll
            for (int e = 0; e < N_EXP; e++) {
                float4 wv = *(const float4*)(rw + e * H_DIM + idx);
                acc[e] += xv.x * wv.x + xv.y * wv.y + xv.z * wv.z + xv.w * wv.w;
            }
        }
#pragma unroll
        for (int s = 32; s > 0; s >>= 1) {
#pragma unroll
            for (int e = 0; e < N_EXP; e++) acc[e] += __shfl_down(acc[e], s);
        }
        if (lane == 0) {
            float l[N_EXP];
#pragma unroll
            for (int e = 0; e < N_EXP; e++) l[e] = acc[e] + rb[e];
            int i1 = 0;
#pragma unroll
            for (int e = 1; e < N_EXP; e++) if (l[e] > l[i1]) i1 = e;
            int i2 = (i1 == 0) ? 1 : 0;
#pragma unroll
            for (int e = 0; e < N_EXP; e++) if (e != i1 && l[e] > l[i2]) i2 = e;
            float w1 = 1.f / (1.f + __expf(l[i2] - l[i1]));
            top2e[t] = i1 | (i2 << 8);
            top2w[t] = make_float2(w1, 1.f - w1);
        }
    }
}

// ---- router phase B: list build + (last block) tile-list build ----
__global__ void k_router_b(const int* __restrict__ top2e, const float2* __restrict__ top2w,
                           int* __restrict__ cnt, int* __restrict__ tokslot,
                           float* __restrict__ pweight, int* __restrict__ done,
                           int4* __restrict__ tiles) {
    __shared__ int lcnt[N_EXP], lbase[N_EXP];
    const int tid = threadIdx.x;
    if (tid < N_EXP) lcnt[tid] = 0;
    __syncthreads();
    const int t = blockIdx.x * 256 + tid;
    const int pe = top2e[t];
    const float2 wv = top2w[t];
    const int e1 = pe & 0xff, e2 = pe >> 8;
    const int s1 = atomicAdd(&lcnt[e1], 1);
    const int s2 = atomicAdd(&lcnt[e2], 1);
    __syncthreads();
    if (tid < N_EXP) lbase[tid] = atomicAdd(&cnt[tid], lcnt[tid]);
    __syncthreads();
    const int p1 = lbase[e1] + s1;
    tokslot[e1 * T_TOK + p1] = t; pweight[e1 * T_TOK + p1] = wv.x;
    const int p2 = lbase[e2] + s2;
    tokslot[e2 * T_TOK + p2] = t | (1 << 16); pweight[e2 * T_TOK + p2] = wv.y;
    __syncthreads();
    if (tid == 0) {
        __threadfence();
        if (atomicAdd(done, 1) == (int)gridDim.x - 1) {
            int c[N_EXP], off = 0, idx = 0;
            for (int e = 0; e < N_EXP; e++) c[e] = atomicAdd(&cnt[e], 0);
            for (int e = 0; e < N_EXP; e++) {
                for (int m0 = 0; m0 < c[e]; m0 += 128)
                    tiles[idx++] = make_int4(e, m0, off, c[e]);
                off += c[e];
            }
            for (; idx < MAXTILE; idx++) tiles[idx] = make_int4(-1, 0, 0, 0);
        }
    }
}

// ---- gate+up fused GEMM: 3-buffer pipeline, raw barrier + vmcnt(4) ----
__launch_bounds__(256, 3)
__global__ void k_gateup(const unsigned short* __restrict__ xb,
                         const unsigned short* __restrict__ wbt,
                         const int4* __restrict__ tiles,
                         const int* __restrict__ tokslot,
                         const float* __restrict__ pweight,
                         unsigned short* __restrict__ hbuf) {
    const int4 td = tiles[blockIdx.x];
    const int e = td.x;
    if (e < 0) return;
    const int m0 = td.y, offe = td.z, cn = td.w;
    const int n0 = blockIdx.y * 64;

    __shared__ __align__(16) unsigned short ldsA[3][128 * 32];
    __shared__ __align__(16) unsigned short ldsB[3][128 * 32];
    __shared__ int tokLds[128];
    __shared__ float pwLds[128];

    const int tid = threadIdx.x;
    if (tid < 128) {
        int gr = m0 + tid;
        int tk = 0; float pw = 0.f;
        if (gr < cn) { tk = tokslot[e * T_TOK + gr] & 0xFFFF; pw = pweight[e * T_TOK + gr]; }
        tokLds[tid] = tk; pwLds[tid] = pw;
    }
    __syncthreads();

    const int lane = tid & 63;
    const int wave = tid >> 6;
    const int fm = lane & 15, quad = lane >> 4;

    const int srow = wave * 16 + (lane >> 2);   // 0..63
    const int scol = (lane & 3) * 8;
    const unsigned short* aG1 = xb + (size_t)tokLds[srow] * H_DIM + scol;
    const unsigned short* aG2 = xb + (size_t)tokLds[64 + srow] * H_DIM + scol;
    const unsigned short* bG1 = wbt + ((size_t)e * 2 * I_DIM + n0 * 2 + srow) * H_DIM + scol;
    const unsigned short* bG2 = bG1 + (size_t)64 * H_DIM;
    const int ldsOff = wave * 512;

    const int wm = (wave & 1) * 64, wnw = wave >> 1;

    v4f acc[4][4];
#pragma unroll
    for (int i = 0; i < 4; i++)
#pragma unroll
        for (int j = 0; j < 4; j++) acc[i][j] = (v4f)0.f;

    const int NIT = H_DIM / 32;   // 24
    // prologue: stage kb=0 -> buf0, kb=1 -> buf1
    async16(aG1, &ldsA[0][ldsOff]);
    async16(aG2, &ldsA[0][2048 + ldsOff]);
    async16(bG1, &ldsB[0][ldsOff]);
    async16(bG2, &ldsB[0][2048 + ldsOff]);
    async16(aG1 + 32, &ldsA[1][ldsOff]);
    async16(aG2 + 32, &ldsA[1][2048 + ldsOff]);
    async16(bG1 + 32, &ldsB[1][ldsOff]);
    async16(bG2 + 32, &ldsB[1][2048 + ldsOff]);

    for (int kb = 0; kb < NIT; kb++) {
        const int cur = kb % 3;
        // outstanding: 8 (kb's 4 oldest + (kb+1)'s 4). Wait for kb's only.
        WAIT_VM4();
        __builtin_amdgcn_s_barrier();   // all waves: buf[cur] complete; buf[(kb+2)%3] free
        {   // prefetch kb+2 (clamped dummy at the tail keeps vmcnt accounting uniform)
            const int kpf = (kb + 2 < NIT ? kb + 2 : NIT - 1) * 32;
            const int nb = (kb + 2) % 3;
            async16(aG1 + kpf, &ldsA[nb][ldsOff]);
            async16(aG2 + kpf, &ldsA[nb][2048 + ldsOff]);
            async16(bG1 + kpf, &ldsB[nb][ldsOff]);
            async16(bG2 + kpf, &ldsB[nb][2048 + ldsOff]);
        }
        v8s aF[4], bF[4];
#pragma unroll
        for (int im = 0; im < 4; im++)
            aF[im] = *(const v8s*)&ldsA[cur][(wm + im * 16 + fm) * 32 + quad * 8];
#pragma unroll
        for (int in = 0; in < 4; in++)
            bF[in] = *(const v8s*)&ldsB[cur][(wnw * 64 + in * 16 + fm) * 32 + quad * 8];
#pragma unroll
        for (int im = 0; im < 4; im++)
#pragma unroll
            for (int in = 0; in < 4; in++)
                acc[im][in] = __builtin_amdgcn_mfma_f32_16x16x32_bf16(aF[im], bF[in], acc[im][in], 0, 0, 0);
    }

    // acc[im][2j]=gate, acc[im][2j+1]=up, cols n0 + wnw*32 + j*16 + fm
#pragma unroll
    for (int im = 0; im < 4; im++) {
#pragma unroll
        for (int reg = 0; reg < 4; reg++) {
            int lr = wm + im * 16 + quad * 4 + reg;
            int gr = m0 + lr;
            if (gr < cn) {
                float pw = pwLds[lr];
                size_t base = (size_t)(offe + gr) * I_DIM + n0 + wnw * 32 + fm;
#pragma unroll
                for (int j = 0; j < 2; j++) {
                    float g = acc[im][2 * j][reg];
                    float u = acc[im][2 * j + 1][reg];
                    float s = g / (1.f + __expf(-g));
                    hbuf[base + j * 16] = f2bf(s * u * pw);
                }
            }
        }
    }
}

// ---- down GEMM: 3-buffer pipeline, raw barrier + vmcnt(4), bf16 stores to ybuf ----
__launch_bounds__(256, 3)
__global__ void k_down(const unsigned short* __restrict__ hbuf,
                       const unsigned short* __restrict__ dbt,
                       const int4* __restrict__ tiles,
                       const int* __restrict__ tokslot,
                       unsigned short* __restrict__ ybuf) {
    const int4 td = tiles[blockIdx.x];
    const int e = td.x;
    if (e < 0) return;
    const int m0 = td.y, offe = td.z, cn = td.w;
    const int n0 = blockIdx.y * 128;

    __shared__ __align__(16) unsigned short ldsA[3][128 * 32];
    __shared__ __align__(16) unsigned short ldsB[3][128 * 32];
    __shared__ int tokLds[128];

    const int tid = threadIdx.x;
    if (tid < 128) {
        int gr = m0 + tid;
        tokLds[tid] = (gr < cn) ? tokslot[e * T_TOK + gr] : 0;
    }
    __syncthreads();

    const int lane = tid & 63;
    const int wave = tid >> 6;
    const int fm = lane & 15, quad = lane >> 4;

    const int srow = wave * 16 + (lane >> 2);
    const int scol = (lane & 3) * 8;
    int ar1 = m0 + srow;      if (ar1 >= cn) ar1 = cn - 1;
    int ar2 = m0 + 64 + srow; if (ar2 >= cn) ar2 = cn - 1;
    const unsigned short* aG1 = hbuf + (size_t)(offe + ar1) * I_DIM + scol;
    const unsigned short* aG2 = hbuf + (size_t)(offe + ar2) * I_DIM + scol;
    const unsigned short* bG1 = dbt + ((size_t)e * H_DIM + n0 + srow) * I_DIM + scol;
    const unsigned short* bG2 = bG1 + (size_t)64 * I_DIM;
    const int ldsOff = wave * 512;

    const int wm = (wave & 1) * 64, wn = (wave >> 1) * 64;

    v4f acc[4][4];
#pragma unroll
    for (int i = 0; i < 4; i++)
#pragma unroll
        for (int j = 0; j < 4; j++) acc[i][j] = (v4f)0.f;

    const int NIT = I_DIM / 32;   // 32
    async16(aG1, &ldsA[0][ldsOff]);
    async16(aG2, &ldsA[0][2048 + ldsOff]);
    async16(bG1, &ldsB[0][ldsOff]);
    async16(bG2, &ldsB[0][2048 + ldsOff]);
    async16(aG1 + 32, &ldsA[1][ldsOff]);
    async16(aG2 + 32, &ldsA[1][2048 + ldsOff]);
    async16(bG1 + 32, &ldsB[1][ldsOff]);
    async16(bG2 + 32, &ldsB[1][2048 + ldsOff]);

    for (int kb = 0; kb < NIT; kb++) {
        const int cur = kb % 3;
        WAIT_VM4();
        __builtin_amdgcn_s_barrier();
        {
            const int kpf = (kb + 2 < NIT ? kb + 2 : NIT - 1) * 32;
            const int nb = (kb + 2) % 3;
            async16(aG1 + kpf, &ldsA[nb][ldsOff]);
            async16(aG2 + kpf, &ldsA[nb][2048 + ldsOff]);
            async16(bG1 + kpf, &ldsB[nb][ldsOff]);
            async16(bG2 + kpf, &ldsB[nb][2048 + ldsOff]);
        }
        v8s aF[4], bF[4];
#pragma unroll
        for (int im = 0; im < 4; im++)
            aF[im] = *(const v8s*)&ldsA[cur][(wm + im * 16 + fm) * 32 + quad * 8];
#pragma unroll
        for (int in = 0; in < 4; in++)
            bF[in] = *(const v8s*)&ldsB[cur][(wn + in * 16 + fm) * 32 + quad * 8];
#pragma unroll
        for (int im = 0; im < 4; im++)
#pragma unroll
            for (int in = 0; in < 4; in++)
                acc[im][in] = __builtin_amdgcn_mfma_f32_16x16x32_bf16(aF[im], bF[in], acc[im][in], 0, 0, 0);
    }

#pragma unroll
    for (int im = 0; im < 4; im++) {
#pragma unroll
        for (int reg = 0; reg < 4; reg++) {
            int lr = wm + im * 16 + quad * 4 + reg;
            int gr = m0 + lr;
            if (gr < cn) {
                int v = tokLds[lr];
                int tok = v & 0xFFFF, s = (v >> 16) & 1;
#pragma unroll
                for (int in = 0; in < 4; in++) {
                    int col = n0 + wn + in * 16 + fm;
                    ybuf[((size_t)s * T_TOK + tok) * H_DIM + col] = f2bf(acc[im][in][reg]);
                }
            }
        }
    }
}

// ---- combine: out = ybuf[0] + ybuf[1], fp32 out ----
__global__ void k_combine(const unsigned short* __restrict__ ybuf, float* __restrict__ out) {
    const size_t i8 = ((size_t)blockIdx.x * 256 + threadIdx.x) * 8;
    const unsigned short* y0 = ybuf + i8;
    const unsigned short* y1 = ybuf + (size_t)T_TOK * H_DIM + i8;
    ushort4 a0 = *(const ushort4*)y0, a1 = *(const ushort4*)(y0 + 4);
    ushort4 b0 = *(const ushort4*)y1, b1 = *(const ushort4*)(y1 + 4);
    float4 o0, o1;
    o0.x = bf2f(a0.x) + bf2f(b0.x); o0.y = bf2f(a0.y) + bf2f(b0.y);
    o0.z = bf2f(a0.z) + bf2f(b0.z); o0.w = bf2f(a0.w) + bf2f(b0.w);
    o1.x = bf2f(a1.x) + bf2f(b1.x); o1.y = bf2f(a1.y) + bf2f(b1.y);
    o1.z = bf2f(a1.z) + bf2f(b1.z); o1.w = bf2f(a1.w) + bf2f(b1.w);
    *(float4*)(out + i8) = o0;
    *(float4*)(out + i8 + 4) = o1;
}

extern "C" void kernel_launch(void* const* d_in, const int* in_sizes, int n_in,
                              void* d_out, int out_size, void* d_ws, size_t ws_size,
                              hipStream_t stream) {
    const float* x  = (const float*)d_in[0];
    const float* rw = (const float*)d_in[1];
    const float* rb = (const float*)d_in[2];
    const float* gw = (const float*)d_in[3];
    const float* uw = (const float*)d_in[4];
    const float* dw = (const float*)d_in[5];
    float* out = (float*)d_out;

    char* ws = (char*)d_ws;
    size_t o = 0;
    auto alloc = [&](size_t bytes) { void* p = ws + o; o += (bytes + 255) & ~255ull; return p; };
    int*    cnt     = (int*)   alloc(8 * 4);              // cnt[5] + done counter
    int*    tokslot = (int*)   alloc((size_t)N_EXP * T_TOK * 4);
    float*  pweight = (float*) alloc((size_t)N_EXP * T_TOK * 4);
    int*    top2e   = (int*)   alloc((size_t)T_TOK * 4);
    float2* top2w   = (float2*)alloc((size_t)T_TOK * 8);
    int4*   tiles   = (int4*)  alloc((size_t)MAXTILE * 16);
    unsigned short* xb   = (unsigned short*)alloc((size_t)T_TOK * H_DIM * 2);
    unsigned short* wbt  = (unsigned short*)alloc((size_t)N_EXP * 2 * I_DIM * H_DIM * 2);
    unsigned short* dbt  = (unsigned short*)alloc((size_t)N_EXP * H_DIM * I_DIM * 2);
    unsigned short* hbuf = (unsigned short*)alloc((size_t)(2 * T_TOK + 128) * I_DIM * 2);
    unsigned short* ybuf = (unsigned short*)alloc((size_t)2 * T_TOK * H_DIM * 2);

    hipMemsetAsync(cnt, 0, 8 * 4, stream);

    // z<15: weight transposes; z in {15,16}: router logits/top2 + x->bf16
    dim3 pg(I_DIM / 32, I_DIM / 32, 3 * N_EXP + 2);
    k_prep<<<pg, 256, 0, stream>>>(gw, uw, dw, wbt, dbt, x, rw, rb, xb, top2e, top2w);

    k_router_b<<<T_TOK / 256, 256, 0, stream>>>(top2e, top2w, cnt, tokslot, pweight,
                                                cnt + 5, tiles);

    dim3 g1(MAXTILE, I_DIM / 64);
    k_gateup<<<g1, 256, 0, stream>>>(xb, wbt, tiles, tokslot, pweight, hbuf);

    dim3 g2(MAXTILE, H_DIM / 128);
    k_down<<<g2, 256, 0, stream>>>(hbuf, dbt, tiles, tokslot, ybuf);

    k_combine<<<(T_TOK * H_DIM) / (256 * 8), 256, 0, stream>>>(ybuf, out);
}

// Round 9
// 241.090 us; speedup vs baseline: 1.1155x; 1.1155x over previous
//
#include <hip/hip_runtime.h>
#include <hip/hip_bf16.h>
#include <cstdint>
#include <cstddef>

#define T_TOK 8192
#define H_DIM 768
#define I_DIM 1024
#define N_EXP 5
#define MAXTILE 136

typedef short v8s __attribute__((ext_vector_type(8)));
typedef float v4f __attribute__((ext_vector_type(4)));

static __device__ __forceinline__ unsigned short f2bf(float f) {
    union { float f; unsigned int u; } v; v.f = f;
    unsigned int u = v.u;
    unsigned int r = (u + 0x7fffu + ((u >> 16) & 1u)) >> 16;
    return (unsigned short)r;
}
static __device__ __forceinline__ float bf2f(unsigned short s) {
    union { unsigned int u; float f; } v; v.u = ((unsigned int)s) << 16; return v.f;
}

// async 16B global->LDS (wave-uniform LDS base + lane*16)
static __device__ __forceinline__ void async16(const unsigned short* g, unsigned short* l) {
    __builtin_amdgcn_global_load_lds(
        (const __attribute__((address_space(1))) unsigned int*)g,
        (__attribute__((address_space(3))) unsigned int*)l, 16, 0, 0);
}

// ---- prep: weight transposes (z<15) + router logits/top2 + x->bf16 (z>=15) ----
__global__ void k_prep(const float* __restrict__ gw, const float* __restrict__ uw,
                       const float* __restrict__ dw,
                       unsigned short* __restrict__ wbt, unsigned short* __restrict__ dbt,
                       const float* __restrict__ x, const float* __restrict__ rw,
                       const float* __restrict__ rb, unsigned short* __restrict__ xb,
                       int* __restrict__ top2e, float2* __restrict__ top2w) {
    const int z = blockIdx.z;
    const int tid = threadIdx.x;
    if (z < 3 * N_EXP) {
        __shared__ float tile[32][33];
        const int row = tid >> 3, cq = tid & 7;
        const int ocol = tid >> 3, seg = tid & 7;
        if (z < 2 * N_EXP) {
            if (blockIdx.y >= H_DIM / 32) return;
            const int e = z % N_EXP;
            const int isUp = z >= N_EXP;
            const float* src = (isUp ? uw : gw) + (size_t)e * H_DIM * I_DIM;
            const int c0 = blockIdx.x * 32, r0 = blockIdx.y * 32;
            float4 v = *(const float4*)(src + (size_t)(r0 + row) * I_DIM + c0 + cq * 4);
            tile[row][cq * 4 + 0] = v.x; tile[row][cq * 4 + 1] = v.y;
            tile[row][cq * 4 + 2] = v.z; tile[row][cq * 4 + 3] = v.w;
            __syncthreads();
            int c = c0 + ocol;
            int orow = (c >> 4) * 32 + (c & 15) + (isUp ? 16 : 0);
            ushort4 o;
            o.x = f2bf(tile[seg * 4 + 0][ocol]); o.y = f2bf(tile[seg * 4 + 1][ocol]);
            o.z = f2bf(tile[seg * 4 + 2][ocol]); o.w = f2bf(tile[seg * 4 + 3][ocol]);
            *(ushort4*)(wbt + ((size_t)e * 2 * I_DIM + orow) * H_DIM + r0 + seg * 4) = o;
        } else {
            if (blockIdx.x >= H_DIM / 32) return;
            const int e = z - 2 * N_EXP;
            const float* src = dw + (size_t)e * I_DIM * H_DIM;
            unsigned short* dst = dbt + (size_t)e * I_DIM * H_DIM;
            const int c0 = blockIdx.x * 32, r0 = blockIdx.y * 32;
            float4 v = *(const float4*)(src + (size_t)(r0 + row) * H_DIM + c0 + cq * 4);
            tile[row][cq * 4 + 0] = v.x; tile[row][cq * 4 + 1] = v.y;
            tile[row][cq * 4 + 2] = v.z; tile[row][cq * 4 + 3] = v.w;
            __syncthreads();
            ushort4 o;
            o.x = f2bf(tile[seg * 4 + 0][ocol]); o.y = f2bf(tile[seg * 4 + 1][ocol]);
            o.z = f2bf(tile[seg * 4 + 2][ocol]); o.w = f2bf(tile[seg * 4 + 3][ocol]);
            *(ushort4*)(dst + (size_t)(c0 + ocol) * I_DIM + r0 + seg * 4) = o;
        }
    } else {
        const int wave = tid >> 6, lane = tid & 63;
        const int t = (((z - 3 * N_EXP) * 1024 + blockIdx.y * 32 + blockIdx.x) * 4) + wave;
        const float* xr = x + (size_t)t * H_DIM;
        unsigned short* xbr = xb + (size_t)t * H_DIM;
        float acc[N_EXP];
#pragma unroll
        for (int e = 0; e < N_EXP; e++) acc[e] = 0.f;
#pragma unroll
        for (int j = 0; j < H_DIM / 256; j++) {
            int idx = j * 256 + lane * 4;
            float4 xv = *(const float4*)(xr + idx);
            ushort4 o;
            o.x = f2bf(xv.x); o.y = f2bf(xv.y); o.z = f2bf(xv.z); o.w = f2bf(xv.w);
            *(ushort4*)(xbr + idx) = o;
#pragma unroll
            for (int e = 0; e < N_EXP; e++) {
                float4 wv = *(const float4*)(rw + e * H_DIM + idx);
                acc[e] += xv.x * wv.x + xv.y * wv.y + xv.z * wv.z + xv.w * wv.w;
            }
        }
#pragma unroll
        for (int s = 32; s > 0; s >>= 1) {
#pragma unroll
            for (int e = 0; e < N_EXP; e++) acc[e] += __shfl_down(acc[e], s);
        }
        if (lane == 0) {
            float l[N_EXP];
#pragma unroll
            for (int e = 0; e < N_EXP; e++) l[e] = acc[e] + rb[e];
            int i1 = 0;
#pragma unroll
            for (int e = 1; e < N_EXP; e++) if (l[e] > l[i1]) i1 = e;
            int i2 = (i1 == 0) ? 1 : 0;
#pragma unroll
            for (int e = 0; e < N_EXP; e++) if (e != i1 && l[e] > l[i2]) i2 = e;
            float w1 = 1.f / (1.f + __expf(l[i2] - l[i1]));
            top2e[t] = i1 | (i2 << 8);
            top2w[t] = make_float2(w1, 1.f - w1);
        }
    }
}

// ---- router phase B: list build + (last block) tile-list build ----
__global__ void k_router_b(const int* __restrict__ top2e, const float2* __restrict__ top2w,
                           int* __restrict__ cnt, int* __restrict__ tokslot,
                           float* __restrict__ pweight, int* __restrict__ done,
                           int4* __restrict__ tiles) {
    __shared__ int lcnt[N_EXP], lbase[N_EXP];
    const int tid = threadIdx.x;
    if (tid < N_EXP) lcnt[tid] = 0;
    __syncthreads();
    const int t = blockIdx.x * 256 + tid;
    const int pe = top2e[t];
    const float2 wv = top2w[t];
    const int e1 = pe & 0xff, e2 = pe >> 8;
    const int s1 = atomicAdd(&lcnt[e1], 1);
    const int s2 = atomicAdd(&lcnt[e2], 1);
    __syncthreads();
    if (tid < N_EXP) lbase[tid] = atomicAdd(&cnt[tid], lcnt[tid]);
    __syncthreads();
    const int p1 = lbase[e1] + s1;
    tokslot[e1 * T_TOK + p1] = t; pweight[e1 * T_TOK + p1] = wv.x;
    const int p2 = lbase[e2] + s2;
    tokslot[e2 * T_TOK + p2] = t | (1 << 16); pweight[e2 * T_TOK + p2] = wv.y;
    __syncthreads();
    if (tid == 0) {
        __threadfence();
        if (atomicAdd(done, 1) == (int)gridDim.x - 1) {
            int c[N_EXP], off = 0, idx = 0;
            for (int e = 0; e < N_EXP; e++) c[e] = atomicAdd(&cnt[e], 0);
            for (int e = 0; e < N_EXP; e++) {
                for (int m0 = 0; m0 < c[e]; m0 += 128)
                    tiles[idx++] = make_int4(e, m0, off, c[e]);
                off += c[e];
            }
            for (; idx < MAXTILE; idx++) tiles[idx] = make_int4(-1, 0, 0, 0);
        }
    }
}

// ---- gate+up fused GEMM: BK=64, XOR-swizzled LDS chunks (conflict-free reads) ----
// LDS row = 128 B = 8 chunks of 16 B. Physical chunk pc at row r holds logical
// chunk pc ^ (r&7). Staged: lane (prow*8+pc) fetches global chunk pc^prow of
// row base+prow. Fragment read of logical chunk L at row r -> phys L^(r&7).
__launch_bounds__(256, 4)
__global__ void k_gateup(const unsigned short* __restrict__ xb,
                         const unsigned short* __restrict__ wbt,
                         const int4* __restrict__ tiles,
                         const int* __restrict__ tokslot,
                         const float* __restrict__ pweight,
                         unsigned short* __restrict__ hbuf) {
    const int4 td = tiles[blockIdx.x];
    const int e = td.x;
    if (e < 0) return;
    const int m0 = td.y, offe = td.z, cn = td.w;
    const int n0 = blockIdx.y * 64;

    __shared__ __align__(16) unsigned short ldsA[128 * 64];
    __shared__ __align__(16) unsigned short ldsB[128 * 64];
    __shared__ int tokLds[128];
    __shared__ float pwLds[128];

    const int tid = threadIdx.x;
    if (tid < 128) {
        int gr = m0 + tid;
        int tk = 0; float pw = 0.f;
        if (gr < cn) { tk = tokslot[e * T_TOK + gr] & 0xFFFF; pw = pweight[e * T_TOK + gr]; }
        tokLds[tid] = tk; pwLds[tid] = pw;
    }
    __syncthreads();

    const int lane = tid & 63;
    const int wave = tid >> 6;
    const int fm = lane & 15, quad = lane >> 4;

    // staging geometry: per call a wave covers 8 rows x 8 chunks
    const int prow = lane >> 3;          // 0..7
    const int pc = lane & 7;             // physical chunk
    const int lc8 = (pc ^ prow) * 8;     // logical chunk offset in shorts

    unsigned aOff[4];
#pragma unroll
    for (int c = 0; c < 4; c++)
        aOff[c] = (unsigned)tokLds[c * 32 + wave * 8 + prow] * H_DIM;
    const unsigned short* aBase = xb + lc8;
    const unsigned short* bBase =
        wbt + ((size_t)e * 2 * I_DIM + n0 * 2 + wave * 8 + prow) * H_DIM + lc8;
    unsigned short* ldsAW = ldsA + wave * 8 * 64;   // + c*32*64
    unsigned short* ldsBW = ldsB + wave * 8 * 64;

    const int wm = (wave & 1) * 64, wnw = wave >> 1;

    v4f acc[4][4];
#pragma unroll
    for (int i = 0; i < 4; i++)
#pragma unroll
        for (int j = 0; j < 4; j++) acc[i][j] = (v4f)0.f;

    for (int kb = 0; kb < H_DIM / 64; kb++) {   // 12 iters
        const int k0 = kb * 64;
#pragma unroll
        for (int c = 0; c < 4; c++)
            async16(aBase + aOff[c] + k0, ldsAW + c * 32 * 64);
#pragma unroll
        for (int c = 0; c < 4; c++)
            async16(bBase + (size_t)c * 32 * H_DIM + k0, ldsBW + c * 32 * 64);
        __syncthreads();
#pragma unroll
        for (int ks = 0; ks < 2; ks++) {
            const int pq = ((ks * 4 + quad) ^ (fm & 7)) * 8;
            v8s aF[4], bF[4];
#pragma unroll
            for (int im = 0; im < 4; im++)
                aF[im] = *(const v8s*)&ldsA[(wm + im * 16 + fm) * 64 + pq];
#pragma unroll
            for (int in = 0; in < 4; in++)
                bF[in] = *(const v8s*)&ldsB[(wnw * 64 + in * 16 + fm) * 64 + pq];
#pragma unroll
            for (int im = 0; im < 4; im++)
#pragma unroll
                for (int in = 0; in < 4; in++)
                    acc[im][in] = __builtin_amdgcn_mfma_f32_16x16x32_bf16(aF[im], bF[in], acc[im][in], 0, 0, 0);
        }
        __syncthreads();
    }

    // acc[im][2j]=gate, acc[im][2j+1]=up, cols n0 + wnw*32 + j*16 + fm
#pragma unroll
    for (int im = 0; im < 4; im++) {
#pragma unroll
        for (int reg = 0; reg < 4; reg++) {
            int lr = wm + im * 16 + quad * 4 + reg;
            int gr = m0 + lr;
            if (gr < cn) {
                float pw = pwLds[lr];
                size_t base = (size_t)(offe + gr) * I_DIM + n0 + wnw * 32 + fm;
#pragma unroll
                for (int j = 0; j < 2; j++) {
                    float g = acc[im][2 * j][reg];
                    float u = acc[im][2 * j + 1][reg];
                    float s = g / (1.f + __expf(-g));
                    hbuf[base + j * 16] = f2bf(s * u * pw);
                }
            }
        }
    }
}

// ---- down GEMM: BK=64, XOR-swizzled, bf16 stores into ybuf[slot][tok][H] ----
__launch_bounds__(256, 4)
__global__ void k_down(const unsigned short* __restrict__ hbuf,
                       const unsigned short* __restrict__ dbt,
                       const int4* __restrict__ tiles,
                       const int* __restrict__ tokslot,
                       unsigned short* __restrict__ ybuf) {
    const int4 td = tiles[blockIdx.x];
    const int e = td.x;
    if (e < 0) return;
    const int m0 = td.y, offe = td.z, cn = td.w;
    const int n0 = blockIdx.y * 128;

    __shared__ __align__(16) unsigned short ldsA[128 * 64];
    __shared__ __align__(16) unsigned short ldsB[128 * 64];
    __shared__ int tokLds[128];

    const int tid = threadIdx.x;
    if (tid < 128) {
        int gr = m0 + tid;
        tokLds[tid] = (gr < cn) ? tokslot[e * T_TOK + gr] : 0;
    }
    __syncthreads();

    const int lane = tid & 63;
    const int wave = tid >> 6;
    const int fm = lane & 15, quad = lane >> 4;

    const int prow = lane >> 3;
    const int pc = lane & 7;
    const int lc8 = (pc ^ prow) * 8;

    unsigned aOff[4];
#pragma unroll
    for (int c = 0; c < 4; c++) {
        int ar = m0 + c * 32 + wave * 8 + prow;
        if (ar >= cn) ar = cn - 1;
        aOff[c] = (unsigned)(offe + ar) * I_DIM;
    }
    const unsigned short* aBase = hbuf + lc8;
    const unsigned short* bBase =
        dbt + ((size_t)e * H_DIM + n0 + wave * 8 + prow) * I_DIM + lc8;
    unsigned short* ldsAW = ldsA + wave * 8 * 64;
    unsigned short* ldsBW = ldsB + wave * 8 * 64;

    const int wm = (wave & 1) * 64, wn = (wave >> 1) * 64;

    v4f acc[4][4];
#pragma unroll
    for (int i = 0; i < 4; i++)
#pragma unroll
        for (int j = 0; j < 4; j++) acc[i][j] = (v4f)0.f;

    for (int kb = 0; kb < I_DIM / 64; kb++) {   // 16 iters
        const int k0 = kb * 64;
#pragma unroll
        for (int c = 0; c < 4; c++)
            async16(aBase + aOff[c] + k0, ldsAW + c * 32 * 64);
#pragma unroll
        for (int c = 0; c < 4; c++)
            async16(bBase + (size_t)c * 32 * I_DIM + k0, ldsBW + c * 32 * 64);
        __syncthreads();
#pragma unroll
        for (int ks = 0; ks < 2; ks++) {
            const int pq = ((ks * 4 + quad) ^ (fm & 7)) * 8;
            v8s aF[4], bF[4];
#pragma unroll
            for (int im = 0; im < 4; im++)
                aF[im] = *(const v8s*)&ldsA[(wm + im * 16 + fm) * 64 + pq];
#pragma unroll
            for (int in = 0; in < 4; in++)
                bF[in] = *(const v8s*)&ldsB[(wn + in * 16 + fm) * 64 + pq];
#pragma unroll
            for (int im = 0; im < 4; im++)
#pragma unroll
                for (int in = 0; in < 4; in++)
                    acc[im][in] = __builtin_amdgcn_mfma_f32_16x16x32_bf16(aF[im], bF[in], acc[im][in], 0, 0, 0);
        }
        __syncthreads();
    }

#pragma unroll
    for (int im = 0; im < 4; im++) {
#pragma unroll
        for (int reg = 0; reg < 4; reg++) {
            int lr = wm + im * 16 + quad * 4 + reg;
            int gr = m0 + lr;
            if (gr < cn) {
                int v = tokLds[lr];
                int tok = v & 0xFFFF, s = (v >> 16) & 1;
#pragma unroll
                for (int in = 0; in < 4; in++) {
                    int col = n0 + wn + in * 16 + fm;
                    ybuf[((size_t)s * T_TOK + tok) * H_DIM + col] = f2bf(acc[im][in][reg]);
                }
            }
        }
    }
}

// ---- combine: out = ybuf[0] + ybuf[1], fp32 out ----
__global__ void k_combine(const unsigned short* __restrict__ ybuf, float* __restrict__ out) {
    const size_t i8 = ((size_t)blockIdx.x * 256 + threadIdx.x) * 8;
    const unsigned short* y0 = ybuf + i8;
    const unsigned short* y1 = ybuf + (size_t)T_TOK * H_DIM + i8;
    ushort4 a0 = *(const ushort4*)y0, a1 = *(const ushort4*)(y0 + 4);
    ushort4 b0 = *(const ushort4*)y1, b1 = *(const ushort4*)(y1 + 4);
    float4 o0, o1;
    o0.x = bf2f(a0.x) + bf2f(b0.x); o0.y = bf2f(a0.y) + bf2f(b0.y);
    o0.z = bf2f(a0.z) + bf2f(b0.z); o0.w = bf2f(a0.w) + bf2f(b0.w);
    o1.x = bf2f(a1.x) + bf2f(b1.x); o1.y = bf2f(a1.y) + bf2f(b1.y);
    o1.z = bf2f(a1.z) + bf2f(b1.z); o1.w = bf2f(a1.w) + bf2f(b1.w);
    *(float4*)(out + i8) = o0;
    *(float4*)(out + i8 + 4) = o1;
}

extern "C" void kernel_launch(void* const* d_in, const int* in_sizes, int n_in,
                              void* d_out, int out_size, void* d_ws, size_t ws_size,
                              hipStream_t stream) {
    const float* x  = (const float*)d_in[0];
    const float* rw = (const float*)d_in[1];
    const float* rb = (const float*)d_in[2];
    const float* gw = (const float*)d_in[3];
    const float* uw = (const float*)d_in[4];
    const float* dw = (const float*)d_in[5];
    float* out = (float*)d_out;

    char* ws = (char*)d_ws;
    size_t o = 0;
    auto alloc = [&](size_t bytes) { void* p = ws + o; o += (bytes + 255) & ~255ull; return p; };
    int*    cnt     = (int*)   alloc(8 * 4);              // cnt[5] + done counter
    int*    tokslot = (int*)   alloc((size_t)N_EXP * T_TOK * 4);
    float*  pweight = (float*) alloc((size_t)N_EXP * T_TOK * 4);
    int*    top2e   = (int*)   alloc((size_t)T_TOK * 4);
    float2* top2w   = (float2*)alloc((size_t)T_TOK * 8);
    int4*   tiles   = (int4*)  alloc((size_t)MAXTILE * 16);
    unsigned short* xb   = (unsigned short*)alloc((size_t)T_TOK * H_DIM * 2);
    unsigned short* wbt  = (unsigned short*)alloc((size_t)N_EXP * 2 * I_DIM * H_DIM * 2);
    unsigned short* dbt  = (unsigned short*)alloc((size_t)N_EXP * H_DIM * I_DIM * 2);
    unsigned short* hbuf = (unsigned short*)alloc((size_t)(2 * T_TOK + 128) * I_DIM * 2);
    unsigned short* ybuf = (unsigned short*)alloc((size_t)2 * T_TOK * H_DIM * 2);

    hipMemsetAsync(cnt, 0, 8 * 4, stream);

    // z<15: weight transposes; z in {15,16}: router logits/top2 + x->bf16
    dim3 pg(I_DIM / 32, I_DIM / 32, 3 * N_EXP + 2);
    k_prep<<<pg, 256, 0, stream>>>(gw, uw, dw, wbt, dbt, x, rw, rb, xb, top2e, top2w);

    k_router_b<<<T_TOK / 256, 256, 0, stream>>>(top2e, top2w, cnt, tokslot, pweight,
                                                cnt + 5, tiles);

    dim3 g1(MAXTILE, I_DIM / 64);
    k_gateup<<<g1, 256, 0, stream>>>(xb, wbt, tiles, tokslot, pweight, hbuf);

    dim3 g2(MAXTILE, H_DIM / 128);
    k_down<<<g2, 256, 0, stream>>>(hbuf, dbt, tiles, tokslot, ybuf);

    k_combine<<<(T_TOK * H_DIM) / (256 * 8), 256, 0, stream>>>(ybuf, out);
}